// Round 4
// baseline (4768.626 us; speedup 1.0000x reference)
//
#include <hip/hip_runtime.h>
#include <math.h>

// Problem constants
#define Bb   64
#define Cc   100
#define Ff   2048
#define Tt   32
#define Hh   300
#define N4P  1216   // 4 gates * H padded to 19*64, interleaved n = 4*col + gate
#define KH   304    // H padded to 19*16 (k dim of recurrent GEMM)
#define NPP  336    // 300 padded to 7*48
#define KOP  304    // 300 padded to 19*16
#define NH   624    // 2*H padded to 13*48 (h0/c0 interleaved n = 2*col + g)
#define BOSi 1

__device__ __forceinline__ float sigmf_(float x){ return 1.0f/(1.0f + expf(-x)); }

__device__ __forceinline__ void fma16_(const float4 av, const float4 bv, float acc[4][4]){
    acc[0][0] += av.x*bv.x; acc[0][1] += av.x*bv.y; acc[0][2] += av.x*bv.z; acc[0][3] += av.x*bv.w;
    acc[1][0] += av.y*bv.x; acc[1][1] += av.y*bv.y; acc[1][2] += av.y*bv.z; acc[1][3] += av.y*bv.w;
    acc[2][0] += av.z*bv.x; acc[2][1] += av.z*bv.y; acc[2][2] += av.z*bv.z; acc[2][3] += av.z*bv.w;
    acc[3][0] += av.w*bv.x; acc[3][1] += av.w*bv.y; acc[3][2] += av.w*bv.z; acc[3][3] += av.w*bv.w;
}

// ---------------------------------------------------------------------------
// Pack (small): W4h_p [KH][N4P] (h-rows of the gate weights, gate-interleaved
// n=4*col+g), b4p[N4P], pb_b[NPP]=bcp+bhp, bhc[NH] (bh0/bc0 interleaved).
// ---------------------------------------------------------------------------
__global__ void k_pack(const float* Wi, const float* Wf, const float* Wo, const float* Wg,
                       const float* bi, const float* bf, const float* bo, const float* bg,
                       const float* bcp, const float* bhp,
                       const float* bh0, const float* bc0,
                       float* W4h_p, float* b4p, float* pb_b, float* bhc)
{
    const int total = KH*N4P + N4P + NPP + NH;
    for (int idx = blockIdx.x*256 + threadIdx.x; idx < total; idx += gridDim.x*256) {
        int i = idx;
        if (i < KH*N4P) {
            int k = i / N4P, n = i % N4P, c = n >> 2, g = n & 3;
            const float* W = (g==0)?Wi:(g==1)?Wf:(g==2)?Wo:Wg;
            // h-block rows of comb are rows Hh..2*Hh-1
            W4h_p[i] = (k < Hh && c < Hh) ? W[(Hh + k)*Hh + c] : 0.0f;
            continue;
        }
        i -= KH*N4P;
        if (i < N4P) {
            int c = i >> 2, g = i & 3;
            const float* bb = (g==0)?bi:(g==1)?bf:(g==2)?bo:bg;
            b4p[i] = (c < Hh) ? bb[c] : 0.0f;
            continue;
        }
        i -= N4P;
        if (i < NPP) {
            pb_b[i] = (i < Hh) ? (bcp[i] + bhp[i]) : 0.0f;
            continue;
        }
        i -= NPP;
        { int c = i >> 1, g = i & 1;
          bhc[i] = (c < Hh) ? (g ? bc0[c] : bh0[c]) : 0.0f; }
    }
}

// ---------------------------------------------------------------------------
// meanT[f][b] = mean over channels. grid (8 f-tiles, 64 b), 256 thr.
// ---------------------------------------------------------------------------
__global__ __launch_bounds__(256) void k_meanT(const float* enc, float* meanT)
{
    const int b = blockIdx.y, f = blockIdx.x*256 + threadIdx.x;
    const float* pe = enc + (b*Cc)*Ff + f;
    float s = 0.0f;
#pragma unroll 10
    for (int c = 0; c < Cc; c++) s += pe[c*Ff];
    meanT[f*64 + b] = s * (1.0f/Cc);
}

// e_enc[b][c] = dot(enc[b,c,:], We_enc). grid (25 c-groups, 64 b), wave per c.
__global__ __launch_bounds__(256) void k_eenc(const float* enc, const float* We_enc, float* e_enc)
{
    const int b = blockIdx.y;
    const int w = threadIdx.x >> 6, lane = threadIdx.x & 63;
    const int c = blockIdx.x*4 + w;
    if (c < Cc) {
        const float* p = enc + (b*Cc + c)*Ff;
        float s = 0.0f;
        for (int k = lane; k < Ff; k += 64) s += p[k]*We_enc[k];
        for (int o = 32; o; o >>= 1) s += __shfl_xor(s, o);
        if (lane == 0) e_enc[b*Cc + c] = s;
    }
}

// ctx[f][b] = sum_c softmax(e_enc[b,:])[c]*enc[b][c][f] -- ONCE.
// The h-dependent energy term is constant over c, so softmax(e_enc) is exact
// and time-invariant. grid (8 f-tiles, 64 b), 256 thr; softmax fused (wave 0).
__global__ __launch_bounds__(256) void k_ctx(const float* enc, const float* e_enc, float* ctxT)
{
    const int b = blockIdx.y, f = blockIdx.x*256 + threadIdx.x;
    __shared__ float sA[128];
    if (threadIdx.x < 64) {
        const int lane = threadIdx.x;
        float v0 = e_enc[b*Cc + lane];
        float v1 = (lane + 64 < Cc) ? e_enc[b*Cc + lane + 64] : -1e30f;
        float m = fmaxf(v0, v1);
        for (int o = 32; o; o >>= 1) m = fmaxf(m, __shfl_xor(m, o));
        float e0 = expf(v0 - m);
        float e1 = (lane + 64 < Cc) ? expf(v1 - m) : 0.0f;
        float s = e0 + e1;
        for (int o = 32; o; o >>= 1) s += __shfl_xor(s, o);
        float inv = 1.0f / s;
        sA[lane] = e0 * inv;
        sA[lane + 64] = e1 * inv;
    }
    __syncthreads();
    const float* pe = enc + (b*Cc)*Ff + f;
    float acc = 0.0f;
#pragma unroll 10
    for (int c = 0; c < Cc; c++) acc += sA[c] * pe[c*Ff];
    ctxT[f*64 + b] = acc;
}

// Embedding gather E[t][j][b], coalesced reads of emb rows.
__global__ void k_embed(const int* caps, const float* emb, float* E)
{
    const int idx = blockIdx.x*256 + threadIdx.x;
    if (idx >= (Tt-1)*Hh*Bb) return;
    const int j = idx % Hh;
    const int bt = idx / Hh;
    const int b = bt / (Tt-1), t = bt % (Tt-1);
    E[(t*Hh + j)*64 + b] = emb[(long)caps[b*Tt + t]*Hh + j];
}

// out[:,0,:] = embedding[BOS]
__global__ void k_bos(const float* emb, float* out)
{
    const int idx = blockIdx.x*256 + threadIdx.x;
    if (idx >= Bb*Hh) return;
    const int b = idx / Hh, j = idx % Hh;
    out[(b*Tt)*Hh + j] = emb[(long)BOSi*Hh + j];
}

// ---------------------------------------------------------------------------
// h0/c0 GEMM: meanT (64 x 2048, k-major) @ [Wh0|Wc0] (2048 x 624 interleaved,
// read raw). grid (13, 8 ksplit), 192 thr.
// ---------------------------------------------------------------------------
__global__ __launch_bounds__(192) void k_gemm_h0(const float* meanT,
                                                 const float* Wh0, const float* Wc0,
                                                 float* parth)
{
    const int nt = blockIdx.x, ks = blockIdx.y, tid = threadIdx.x;
    const int n0 = nt*48, tx = tid % 12, ty = tid / 12;
    __shared__ float As[16][64];
    __shared__ float Bs[16][48];
    float acc[4][4] = {};
    const int k0 = ks*256;
    for (int kb = 0; kb < 16; kb++) {
        const int kbase = k0 + kb*16;
        for (int idx = tid; idx < 1024; idx += 192) {
            int kk = idx >> 6, bb = idx & 63;
            As[kk][bb] = meanT[(kbase + kk)*64 + bb];
        }
        for (int idx = tid; idx < 768; idx += 192) {
            int kk = idx / 48, nn = idx % 48;
            int n = n0 + nn, col = n >> 1;
            const float* W = (n & 1) ? Wc0 : Wh0;
            Bs[kk][nn] = (col < Hh) ? W[(kbase + kk)*Hh + col] : 0.0f;
        }
        __syncthreads();
#pragma unroll
        for (int kk = 0; kk < 16; kk++) {
            float4 av = *(const float4*)&As[kk][ty*4];
            float4 bv = *(const float4*)&Bs[kk][tx*4];
            fma16_(av, bv, acc);
        }
        __syncthreads();
    }
#pragma unroll
    for (int i = 0; i < 4; i++)
        *(float4*)&parth[(ks*64 + ty*4 + i)*NH + n0 + tx*4]
            = make_float4(acc[i][0], acc[i][1], acc[i][2], acc[i][3]);
}

// h0/c0 epilogue: hT[0][col][b] = tanh, c0T[col][b] = tanh. grid 64 (b), 256 thr.
__global__ __launch_bounds__(256) void k_h0fin2(const float* parth, const float* bhc,
                                                float* hT, float* c0T)
{
    const int b = blockIdx.x, tid = threadIdx.x;
    for (int col = tid; col < Hh; col += 256) {
        float sh = bhc[2*col], sc = bhc[2*col+1];
        for (int ks = 0; ks < 8; ks++) {
            const float2 v = *(const float2*)&parth[(ks*64 + b)*NH + 2*col];
            sh += v.x; sc += v.y;
        }
        hT[(0*Hh + col)*64 + b] = tanhf(sh);
        c0T[col*64 + b] = tanhf(sc);
    }
}

// ---------------------------------------------------------------------------
// C partials: ctx (64 x 2048 k-major) @ W4c (2048 x 1216, gate-interleaved,
// read raw from Wi..Wg rows 600..2647). grid (19 nt, 8 ks), 256 thr, 64x64 tile.
// Output partC[ks][n][b].
// ---------------------------------------------------------------------------
__global__ __launch_bounds__(256) void k_gemm_C(const float* ctxT,
                                                const float* Wi, const float* Wf,
                                                const float* Wo, const float* Wg,
                                                float* partC)
{
    const int nt = blockIdx.x, ks = blockIdx.y, tid = threadIdx.x;
    const int n0 = nt*64, tx = tid & 15, ty = tid >> 4;
    __shared__ float As[16][64];
    __shared__ float Bs[16][64];
    float acc[4][4] = {};
    const int k0 = ks*256;
    for (int kb = 0; kb < 16; kb++) {
        const int kbase = k0 + kb*16;
#pragma unroll
        for (int i = 0; i < 4; i++) {
            int idx = tid + i*256;
            int kk = idx >> 6, bb = idx & 63;
            As[kk][bb] = ctxT[(kbase + kk)*64 + bb];
        }
#pragma unroll
        for (int i = 0; i < 4; i++) {
            int idx = tid + i*256;
            int kk = idx >> 6, nn = idx & 63;
            int n = n0 + nn, c = n >> 2, g = n & 3;
            const float* W = (g==0)?Wi:(g==1)?Wf:(g==2)?Wo:Wg;
            Bs[kk][nn] = (c < Hh) ? W[(2*Hh + kbase + kk)*Hh + c] : 0.0f;
        }
        __syncthreads();
#pragma unroll
        for (int kk = 0; kk < 16; kk++) {
            float4 av = *(const float4*)&As[kk][ty*4];
            float4 bv = *(const float4*)&Bs[kk][tx*4];
            fma16_(av, bv, acc);
        }
        __syncthreads();
    }
#pragma unroll
    for (int jn = 0; jn < 4; jn++) {
        float4 v = make_float4(acc[0][jn], acc[1][jn], acc[2][jn], acc[3][jn]);
        *(float4*)&partC[((ks*N4P) + n0 + tx*4 + jn)*64 + ty*4] = v;
    }
}

// ---------------------------------------------------------------------------
// gpre[t][b][n] = (E_t @ W4e)[b][n] + sum_ks partC[ks][n][b] + b4p[n].
// grid (19 nt, 31 t), 256 thr, 64x64 tile, K=304 single pass.
// NOTE output layout [t][b][n] so the recurrence reads coalesced over n.
// ---------------------------------------------------------------------------
__global__ __launch_bounds__(256) void k_gemm_gpre(const float* E,
                                                   const float* Wi, const float* Wf,
                                                   const float* Wo, const float* Wg,
                                                   const float* partC, const float* b4p,
                                                   float* gpre)
{
    const int nt = blockIdx.x, t = blockIdx.y, tid = threadIdx.x;
    const int n0 = nt*64, tx = tid & 15, ty = tid >> 4;
    __shared__ float As[16][64];
    __shared__ float Bs[16][64];
    float acc[4][4] = {};
    for (int kb = 0; kb < 19; kb++) {
        const int kbase = kb*16;
#pragma unroll
        for (int i = 0; i < 4; i++) {
            int idx = tid + i*256;
            int kk = idx >> 6, bb = idx & 63, j = kbase + kk;
            As[kk][bb] = (j < Hh) ? E[(t*Hh + j)*64 + bb] : 0.0f;
        }
#pragma unroll
        for (int i = 0; i < 4; i++) {
            int idx = tid + i*256;
            int kk = idx >> 6, nn = idx & 63, j = kbase + kk;
            int n = n0 + nn, c = n >> 2, g = n & 3;
            const float* W = (g==0)?Wi:(g==1)?Wf:(g==2)?Wo:Wg;
            Bs[kk][nn] = (j < Hh && c < Hh) ? W[j*Hh + c] : 0.0f;
        }
        __syncthreads();
#pragma unroll
        for (int kk = 0; kk < 16; kk++) {
            float4 av = *(const float4*)&As[kk][ty*4];
            float4 bv = *(const float4*)&Bs[kk][tx*4];
            fma16_(av, bv, acc);
        }
        __syncthreads();
    }
#pragma unroll
    for (int i = 0; i < 4; i++) {
        const int n = n0 + tx*4;
        float4 ps0 = make_float4(0,0,0,0);
        for (int ks = 0; ks < 8; ks++) {
            ps0.x += partC[(ks*N4P + n + 0)*64 + ty*4 + i];
            ps0.y += partC[(ks*N4P + n + 1)*64 + ty*4 + i];
            ps0.z += partC[(ks*N4P + n + 2)*64 + ty*4 + i];
            ps0.w += partC[(ks*N4P + n + 3)*64 + ty*4 + i];
        }
        float4 o;
        o.x = acc[i][0] + ps0.x + b4p[n+0];
        o.y = acc[i][1] + ps0.y + b4p[n+1];
        o.z = acc[i][2] + ps0.z + b4p[n+2];
        o.w = acc[i][3] + ps0.w + b4p[n+3];
        *(float4*)&gpre[((long)(t*64 + ty*4 + i))*N4P + n] = o;
    }
}

// ---------------------------------------------------------------------------
// pbias partials: ctx @ Wcp (2048 x 300, raw). grid (7 nt, 8 ks), 192 thr.
// Output ppb[ks][n(336)][b].
// ---------------------------------------------------------------------------
__global__ __launch_bounds__(192) void k_gemm_pb(const float* ctxT, const float* Wcp,
                                                 float* ppb)
{
    const int nt = blockIdx.x, ks = blockIdx.y, tid = threadIdx.x;
    const int n0 = nt*48, tx = tid % 12, ty = tid / 12;
    __shared__ float As[16][64];
    __shared__ float Bs[16][48];
    float acc[4][4] = {};
    const int k0 = ks*256;
    for (int kb = 0; kb < 16; kb++) {
        const int kbase = k0 + kb*16;
        for (int idx = tid; idx < 1024; idx += 192) {
            int kk = idx >> 6, bb = idx & 63;
            As[kk][bb] = ctxT[(kbase + kk)*64 + bb];
        }
        for (int idx = tid; idx < 768; idx += 192) {
            int kk = idx / 48, nn = idx % 48, n = n0 + nn;
            Bs[kk][nn] = (n < Hh) ? Wcp[(kbase + kk)*Hh + n] : 0.0f;
        }
        __syncthreads();
#pragma unroll
        for (int kk = 0; kk < 16; kk++) {
            float4 av = *(const float4*)&As[kk][ty*4];
            float4 bv = *(const float4*)&Bs[kk][tx*4];
            fma16_(av, bv, acc);
        }
        __syncthreads();
    }
#pragma unroll
    for (int jn = 0; jn < 4; jn++) {
        float4 v = make_float4(acc[0][jn], acc[1][jn], acc[2][jn], acc[3][jn]);
        *(float4*)&ppb[((ks*NPP) + n0 + tx*4 + jn)*64 + ty*4] = v;
    }
}

// ---------------------------------------------------------------------------
// Recurrence: one WG per PAIR of batch elements (grid 32 x 1024 thr), no grid
// sync (batch elements are independent). Weights are STREAMED from L2 each
// step (1.46 MB/WG/step -- L2-resident, coalesced); no big per-thread arrays,
// so nothing can spill. h lives in LDS (broadcast reads); cell state is one
// register per owning thread. Gate nonlinearity for b0/b1 runs on disjoint
// thread ranges (0..299 and 512..811).
// Column map: thread tid owns col tid (0..1023); threads 832..1023 also own
// col tid+192 (= 1024..1215).
// ---------------------------------------------------------------------------
__global__ __launch_bounds__(1024) void k_recb(const float* __restrict__ W4h_p,
                                               const float* __restrict__ gpre,
                                               const float* __restrict__ c0T,
                                               float* __restrict__ hT)
{
    const int b0 = blockIdx.x*2, b1 = b0 + 1;
    const int tid = threadIdx.x;
    __shared__ float hbuf0[304], hbuf1[304];
    __shared__ float sg[2432];                 // [2][1216] gate pre-activations

    float cst = 0.0f;                          // c for (b0,col=tid) or (b1,col=tid-512)
    if (tid < Hh) {
        cst = c0T[tid*64 + b0];
        hbuf0[tid] = hT[tid*64 + b0];
    } else if (tid >= 512 && tid < 512 + Hh) {
        const int j = tid - 512;
        cst = c0T[j*64 + b1];
        hbuf1[j] = hT[j*64 + b1];
    }
    __syncthreads();

    const int col2 = tid + 192;                // extra col for tid >= 832

    for (int t = 1; t < Tt; t++) {
        const float* gp0 = gpre + ((long)((t-1)*64 + b0))*N4P;
        const float* gp1 = gpre + ((long)((t-1)*64 + b1))*N4P;

        // main column tid
        {
            const float* wc = W4h_p + tid;
            float a0 = 0.0f, a1 = 0.0f;
#pragma unroll
            for (int k = 0; k < 300; k += 4) {
                const float4 h0 = *(const float4*)&hbuf0[k];
                const float4 h1 = *(const float4*)&hbuf1[k];
                const float w0 = wc[(k+0)*N4P];
                const float w1 = wc[(k+1)*N4P];
                const float w2 = wc[(k+2)*N4P];
                const float w3 = wc[(k+3)*N4P];
                a0 += w0*h0.x + w1*h0.y + w2*h0.z + w3*h0.w;
                a1 += w0*h1.x + w1*h1.y + w2*h1.z + w3*h1.w;
            }
            sg[tid]        = a0 + gp0[tid];
            sg[1216 + tid] = a1 + gp1[tid];
        }
        // extra columns 1024..1215 (threads 832..1023)
        if (tid >= 832) {
            const float* wc = W4h_p + col2;
            float a0 = 0.0f, a1 = 0.0f;
#pragma unroll
            for (int k = 0; k < 300; k += 4) {
                const float4 h0 = *(const float4*)&hbuf0[k];
                const float4 h1 = *(const float4*)&hbuf1[k];
                const float w0 = wc[(k+0)*N4P];
                const float w1 = wc[(k+1)*N4P];
                const float w2 = wc[(k+2)*N4P];
                const float w3 = wc[(k+3)*N4P];
                a0 += w0*h0.x + w1*h0.y + w2*h0.z + w3*h0.w;
                a1 += w0*h1.x + w1*h1.y + w2*h1.z + w3*h1.w;
            }
            sg[col2]        = a0 + gp0[col2];
            sg[1216 + col2] = a1 + gp1[col2];
        }
        __syncthreads();

        // gate nonlinearity: b0 on threads 0..299, b1 on threads 512..811
        if (tid < Hh) {
            const float4 s = *(const float4*)&sg[4*tid];
            const float ig = sigmf_(s.x), fg = sigmf_(s.y), og = sigmf_(s.z);
            const float gg = tanhf(s.w);
            cst = fg*cst + ig*gg;
            const float h = og*tanhf(cst);
            hT[(t*Hh + tid)*64 + b0] = h;
            hbuf0[tid] = h;
        } else if (tid >= 512 && tid < 512 + Hh) {
            const int j = tid - 512;
            const float4 s = *(const float4*)&sg[1216 + 4*j];
            const float ig = sigmf_(s.x), fg = sigmf_(s.y), og = sigmf_(s.z);
            const float gg = tanhf(s.w);
            cst = fg*cst + ig*gg;
            const float h = og*tanhf(cst);
            hT[(t*Hh + j)*64 + b1] = h;
            hbuf1[j] = h;
        }
        __syncthreads();
    }
}

// ---------------------------------------------------------------------------
// tmp[t][j][b] = E[t][j][b] + (h_{t+1} @ Whp)[j][b] + pbias[j][b].
// grid (7 nt, 31 t), 192 thr, K=304.
// ---------------------------------------------------------------------------
__global__ __launch_bounds__(192) void k_gemm_tmp(const float* hT, const float* Whp,
                                                  const float* E, const float* ppb,
                                                  const float* pb_b, float* tmpT)
{
    const int nt = blockIdx.x, ti = blockIdx.y, tid = threadIdx.x;
    const int n0 = nt*48, tx = tid % 12, ty = tid / 12;
    __shared__ float As[16][64];
    __shared__ float Bs[16][48];
    float acc[4][4] = {};
    for (int kb = 0; kb < 19; kb++) {
        const int kbase = kb*16;
        for (int idx = tid; idx < 1024; idx += 192) {
            int kk = idx >> 6, bb = idx & 63, j = kbase + kk;
            As[kk][bb] = (j < Hh) ? hT[((ti+1)*Hh + j)*64 + bb] : 0.0f;
        }
        for (int idx = tid; idx < 768; idx += 192) {
            int kk = idx / 48, nn = idx % 48, j = kbase + kk, n = n0 + nn;
            Bs[kk][nn] = (j < Hh && n < Hh) ? Whp[j*Hh + n] : 0.0f;
        }
        __syncthreads();
#pragma unroll
        for (int kk = 0; kk < 16; kk++) {
            float4 av = *(const float4*)&As[kk][ty*4];
            float4 bv = *(const float4*)&Bs[kk][tx*4];
            fma16_(av, bv, acc);
        }
        __syncthreads();
    }
#pragma unroll
    for (int i = 0; i < 4; i++) {
        const int bb = ty*4 + i;
#pragma unroll
        for (int j = 0; j < 4; j++) {
            const int n = n0 + tx*4 + j;
            if (n < KOP) {
                float v = acc[i][j];
                if (n < Hh) {
                    float pb = pb_b[n];
                    for (int ks = 0; ks < 8; ks++) pb += ppb[(ks*NPP + n)*64 + bb];
                    v += E[(ti*Hh + n)*64 + bb] + pb;
                }
                tmpT[(ti*KOP + n)*64 + bb] = v;
            }
        }
    }
}

// Stage B: out[:, t+1, :] = tmp @ Wop + bop (raw). grid (7 ntiles, 31 t).
__global__ __launch_bounds__(192) void k_predb(const float* tmpT, const float* Wop,
                                               const float* bop, float* out)
{
    const int nt = blockIdx.x, ti = blockIdx.y, tid = threadIdx.x;
    const int n0 = nt*48, tx = tid % 12, ty = tid / 12;
    __shared__ float As[16][64];
    __shared__ float Bs[16][48];
    float acc[4][4] = {};
    const float* Asrc = tmpT + ti*KOP*64;

    for (int kb = 0; kb < 19; kb++) {
        const int kbase = kb*16;
        for (int idx = tid; idx < 1024; idx += 192) {
            int kk = idx >> 6, bb = idx & 63;
            As[kk][bb] = Asrc[(kbase + kk)*64 + bb];
        }
        for (int idx = tid; idx < 768; idx += 192) {
            int kk = idx / 48, nn = idx % 48, j = kbase + kk, n = n0 + nn;
            Bs[kk][nn] = (j < Hh && n < Hh) ? Wop[j*Hh + n] : 0.0f;
        }
        __syncthreads();
#pragma unroll
        for (int kk = 0; kk < 16; kk++) {
            float4 av = *(const float4*)&As[kk][ty*4];
            float4 bv = *(const float4*)&Bs[kk][tx*4];
            fma16_(av, bv, acc);
        }
        __syncthreads();
    }
#pragma unroll
    for (int i = 0; i < 4; i++) {
        const int bb = ty*4 + i;
#pragma unroll
        for (int j = 0; j < 4; j++) {
            const int n = n0 + tx*4 + j;
            if (n < Hh)
                out[(bb*Tt + (ti+1))*Hh + n] = acc[i][j] + bop[n];
        }
    }
}

// ---------------------------------------------------------------------------
extern "C" void kernel_launch(void* const* d_in, const int* in_sizes, int n_in,
                              void* d_out, int out_size, void* d_ws, size_t ws_size,
                              hipStream_t stream)
{
    const float* enc    = (const float*)d_in[0];
    const int*   caps   = (const int*)  d_in[1];
    const float* emb    = (const float*)d_in[2];
    const float* Wh0    = (const float*)d_in[3];
    const float* bh0    = (const float*)d_in[4];
    const float* Wc0    = (const float*)d_in[5];
    const float* bc0    = (const float*)d_in[6];
    const float* We_enc = (const float*)d_in[7];
    const float* We_hid = (const float*)d_in[8];
    const float* be     = (const float*)d_in[9];
    const float* Wi     = (const float*)d_in[10];
    const float* bi     = (const float*)d_in[11];
    const float* Wf     = (const float*)d_in[12];
    const float* bf     = (const float*)d_in[13];
    const float* Wo     = (const float*)d_in[14];
    const float* bo     = (const float*)d_in[15];
    const float* Wg     = (const float*)d_in[16];
    const float* bg     = (const float*)d_in[17];
    const float* Wcp    = (const float*)d_in[18];
    const float* bcp    = (const float*)d_in[19];
    const float* Whp    = (const float*)d_in[20];
    const float* bhp    = (const float*)d_in[21];
    const float* Wop    = (const float*)d_in[22];
    const float* bop    = (const float*)d_in[23];
    float* out = (float*)d_out;
    (void)We_hid; (void)be;   // softmax is invariant to the h-term: unused.

    // Workspace carve-up (floats).
    float* w = (float*)d_ws;
    float* W4h_p = w; w += KH*N4P;       //   369,664
    float* b4p   = w; w += N4P;
    float* pb_b  = w; w += NPP;
    float* bhc   = w; w += NH;
    float* e_enc = w; w += Bb*Cc;
    float* ctxT  = w; w += Ff*64;        //   131,072
    float* hT    = w; w += Tt*Hh*64;     //   614,400  h_t, t=0..31, [t][col][b]
    float* E     = w; w += 31*Hh*64;     //   595,200  emb_prev, [t][j][b]
    float* c0T   = w; w += KH*64;        //    19,456  [col][b]
    float* gpre  = w; w += 31*64*N4P;    // 2,412,544  [t][b][n]
    float* partC = w; w += 8*N4P*64;     //   622,592  [ks][n][b]
    float* ppb   = w; w += 8*NPP*64;     //   172,032  [ks][n][b]
    float* tmpT  = w; w += 31*KOP*64;    //   603,136  [t][j][b]
    // init-phase aliases (dead before tmpT is written by k_gemm_tmp)
    float* meanT = tmpT;                 // 131,072
    float* parth = tmpT + 131072;        // 319,488 (fits 603,136)
    (void)ws_size; (void)in_sizes; (void)n_in; (void)out_size;

    k_pack<<<512, 256, 0, stream>>>(Wi, Wf, Wo, Wg, bi, bf, bo, bg,
                                    bcp, bhp, bh0, bc0,
                                    W4h_p, b4p, pb_b, bhc);
    k_meanT<<<dim3(8, 64), 256, 0, stream>>>(enc, meanT);
    k_eenc <<<dim3(25, 64), 256, 0, stream>>>(enc, We_enc, e_enc);
    k_embed<<<2325, 256, 0, stream>>>(caps, emb, E);
    k_bos  <<<75, 256, 0, stream>>>(emb, out);
    k_ctx  <<<dim3(8, 64), 256, 0, stream>>>(enc, e_enc, ctxT);
    k_gemm_h0<<<dim3(13, 8), 192, 0, stream>>>(meanT, Wh0, Wc0, parth);
    k_h0fin2<<<64, 256, 0, stream>>>(parth, bhc, hT, c0T);
    k_gemm_C<<<dim3(19, 8), 256, 0, stream>>>(ctxT, Wi, Wf, Wo, Wg, partC);
    k_gemm_gpre<<<dim3(19, 31), 256, 0, stream>>>(E, Wi, Wf, Wo, Wg, partC, b4p, gpre);
    k_gemm_pb<<<dim3(7, 8), 192, 0, stream>>>(ctxT, Wcp, ppb);

    // Recurrence: 32 independent 2-batch workgroups, weights streamed from L2.
    k_recb<<<32, 1024, 0, stream>>>(W4h_p, gpre, c0T, hT);

    k_gemm_tmp<<<dim3(7, 31), 192, 0, stream>>>(hT, Whp, E, ppb, pb_b, tmpT);
    k_predb<<<dim3(7, 31), 192, 0, stream>>>(tmpT, Wop, bop, out);
}

// Round 5
// 949.701 us; speedup vs baseline: 5.0212x; 5.0212x over previous
//
#include <hip/hip_runtime.h>
#include <math.h>

// Problem constants
#define Bb   64
#define Cc   100
#define Ff   2048
#define Tt   32
#define Hh   300
#define N4P  1216   // 4 gates * H padded to 19*64, interleaved n = 4*col + gate
#define KH   304    // H padded to 19*16
#define NPP  336    // 300 padded to 7*48
#define KOP  304    // 300 padded to 19*16
#define NH   624    // 2*H padded to 13*48 (h0/c0 interleaved n = 2*col + g)
#define BOSi 1
#define NWG  75     // recurrence workgroups (75 * 4 hcols = 300)

__device__ __forceinline__ float sigmf_(float x){ return 1.0f/(1.0f + expf(-x)); }

__device__ __forceinline__ void fma16_(const float4 av, const float4 bv, float acc[4][4]){
    acc[0][0] += av.x*bv.x; acc[0][1] += av.x*bv.y; acc[0][2] += av.x*bv.z; acc[0][3] += av.x*bv.w;
    acc[1][0] += av.y*bv.x; acc[1][1] += av.y*bv.y; acc[1][2] += av.y*bv.z; acc[1][3] += av.y*bv.w;
    acc[2][0] += av.z*bv.x; acc[2][1] += av.z*bv.y; acc[2][2] += av.z*bv.z; acc[2][3] += av.z*bv.w;
    acc[3][0] += av.w*bv.x; acc[3][1] += av.w*bv.y; acc[3][2] += av.w*bv.z; acc[3][3] += av.w*bv.w;
}

// ---------------------------------------------------------------------------
// Pack (small): W4h_p [KH][N4P] (h-rows of gate weights, n=4*col+g), b4p,
// pb_b = bcp+bhp, bhc (bh0/bc0 interleaved), and recurrence flag init.
// ---------------------------------------------------------------------------
__global__ void k_pack(const float* Wi, const float* Wf, const float* Wo, const float* Wg,
                       const float* bi, const float* bf, const float* bo, const float* bg,
                       const float* bcp, const float* bhp,
                       const float* bh0, const float* bc0,
                       float* W4h_p, float* b4p, float* pb_b, float* bhc, int* flags)
{
    const int total = KH*N4P + N4P + NPP + NH + 128;
    for (int idx = blockIdx.x*256 + threadIdx.x; idx < total; idx += gridDim.x*256) {
        int i = idx;
        if (i < KH*N4P) {
            int k = i / N4P, n = i % N4P, c = n >> 2, g = n & 3;
            const float* W = (g==0)?Wi:(g==1)?Wf:(g==2)?Wo:Wg;
            W4h_p[i] = (k < Hh && c < Hh) ? W[(Hh + k)*Hh + c] : 0.0f;
            continue;
        }
        i -= KH*N4P;
        if (i < N4P) {
            int c = i >> 2, g = i & 3;
            const float* bb = (g==0)?bi:(g==1)?bf:(g==2)?bo:bg;
            b4p[i] = (c < Hh) ? bb[c] : 0.0f;
            continue;
        }
        i -= N4P;
        if (i < NPP) {
            pb_b[i] = (i < Hh) ? (bcp[i] + bhp[i]) : 0.0f;
            continue;
        }
        i -= NPP;
        if (i < NH) {
            int c = i >> 1, g = i & 1;
            bhc[i] = (c < Hh) ? (g ? bc0[c] : bh0[c]) : 0.0f;
            continue;
        }
        i -= NH;
        flags[i] = (i < NWG) ? 0 : 0x7fffffff;   // reset every launch
    }
}

// ---------------------------------------------------------------------------
// meanT[f][b] = mean over channels. grid (8 f-tiles, 64 b), 256 thr.
// ---------------------------------------------------------------------------
__global__ __launch_bounds__(256) void k_meanT(const float* enc, float* meanT)
{
    const int b = blockIdx.y, f = blockIdx.x*256 + threadIdx.x;
    const float* pe = enc + (b*Cc)*Ff + f;
    float s = 0.0f;
#pragma unroll 10
    for (int c = 0; c < Cc; c++) s += pe[c*Ff];
    meanT[f*64 + b] = s * (1.0f/Cc);
}

// e_enc[b][c] = dot(enc[b,c,:], We_enc). grid (25 c-groups, 64 b), wave per c.
__global__ __launch_bounds__(256) void k_eenc(const float* enc, const float* We_enc, float* e_enc)
{
    const int b = blockIdx.y;
    const int w = threadIdx.x >> 6, lane = threadIdx.x & 63;
    const int c = blockIdx.x*4 + w;
    if (c < Cc) {
        const float* p = enc + (b*Cc + c)*Ff;
        float s = 0.0f;
        for (int k = lane; k < Ff; k += 64) s += p[k]*We_enc[k];
        for (int o = 32; o; o >>= 1) s += __shfl_xor(s, o);
        if (lane == 0) e_enc[b*Cc + c] = s;
    }
}

// ctx[f][b] = sum_c softmax(e_enc[b,:])[c]*enc[b][c][f] -- ONCE.
// (h-term of the energy is constant over c => softmax is time-invariant.)
__global__ __launch_bounds__(256) void k_ctx(const float* enc, const float* e_enc, float* ctxT)
{
    const int b = blockIdx.y, f = blockIdx.x*256 + threadIdx.x;
    __shared__ float sA[128];
    if (threadIdx.x < 64) {
        const int lane = threadIdx.x;
        float v0 = e_enc[b*Cc + lane];
        float v1 = (lane + 64 < Cc) ? e_enc[b*Cc + lane + 64] : -1e30f;
        float m = fmaxf(v0, v1);
        for (int o = 32; o; o >>= 1) m = fmaxf(m, __shfl_xor(m, o));
        float e0 = expf(v0 - m);
        float e1 = (lane + 64 < Cc) ? expf(v1 - m) : 0.0f;
        float s = e0 + e1;
        for (int o = 32; o; o >>= 1) s += __shfl_xor(s, o);
        float inv = 1.0f / s;
        sA[lane] = e0 * inv;
        sA[lane + 64] = e1 * inv;
    }
    __syncthreads();
    const float* pe = enc + (b*Cc)*Ff + f;
    float acc = 0.0f;
#pragma unroll 10
    for (int c = 0; c < Cc; c++) acc += sA[c] * pe[c*Ff];
    ctxT[f*64 + b] = acc;
}

// Embedding gather E[t][j][b].
__global__ void k_embed(const int* caps, const float* emb, float* E)
{
    const int idx = blockIdx.x*256 + threadIdx.x;
    if (idx >= (Tt-1)*Hh*Bb) return;
    const int j = idx % Hh;
    const int bt = idx / Hh;
    const int b = bt / (Tt-1), t = bt % (Tt-1);
    E[(t*Hh + j)*64 + b] = emb[(long)caps[b*Tt + t]*Hh + j];
}

// out[:,0,:] = embedding[BOS]
__global__ void k_bos(const float* emb, float* out)
{
    const int idx = blockIdx.x*256 + threadIdx.x;
    if (idx >= Bb*Hh) return;
    const int b = idx / Hh, j = idx % Hh;
    out[(b*Tt)*Hh + j] = emb[(long)BOSi*Hh + j];
}

// ---------------------------------------------------------------------------
// h0/c0 GEMM: meanT (64 x 2048) @ [Wh0|Wc0] (2048 x 624). grid (13, 8).
// ---------------------------------------------------------------------------
__global__ __launch_bounds__(192) void k_gemm_h0(const float* meanT,
                                                 const float* Wh0, const float* Wc0,
                                                 float* parth)
{
    const int nt = blockIdx.x, ks = blockIdx.y, tid = threadIdx.x;
    const int n0 = nt*48, tx = tid % 12, ty = tid / 12;
    __shared__ float As[16][64];
    __shared__ float Bs[16][48];
    float acc[4][4] = {};
    const int k0 = ks*256;
    for (int kb = 0; kb < 16; kb++) {
        const int kbase = k0 + kb*16;
        for (int idx = tid; idx < 1024; idx += 192) {
            int kk = idx >> 6, bb = idx & 63;
            As[kk][bb] = meanT[(kbase + kk)*64 + bb];
        }
        for (int idx = tid; idx < 768; idx += 192) {
            int kk = idx / 48, nn = idx % 48;
            int n = n0 + nn, col = n >> 1;
            const float* W = (n & 1) ? Wc0 : Wh0;
            Bs[kk][nn] = (col < Hh) ? W[(kbase + kk)*Hh + col] : 0.0f;
        }
        __syncthreads();
#pragma unroll
        for (int kk = 0; kk < 16; kk++) {
            float4 av = *(const float4*)&As[kk][ty*4];
            float4 bv = *(const float4*)&Bs[kk][tx*4];
            fma16_(av, bv, acc);
        }
        __syncthreads();
    }
#pragma unroll
    for (int i = 0; i < 4; i++)
        *(float4*)&parth[(ks*64 + ty*4 + i)*NH + n0 + tx*4]
            = make_float4(acc[i][0], acc[i][1], acc[i][2], acc[i][3]);
}

// h0/c0 epilogue. grid 64 (b), 256 thr.
__global__ __launch_bounds__(256) void k_h0fin2(const float* parth, const float* bhc,
                                                float* hT, float* c0T)
{
    const int b = blockIdx.x, tid = threadIdx.x;
    for (int col = tid; col < Hh; col += 256) {
        float sh = bhc[2*col], sc = bhc[2*col+1];
        for (int ks = 0; ks < 8; ks++) {
            const float2 v = *(const float2*)&parth[(ks*64 + b)*NH + 2*col];
            sh += v.x; sc += v.y;
        }
        hT[(0*Hh + col)*64 + b] = tanhf(sh);
        c0T[col*64 + b] = tanhf(sc);
    }
}

// ---------------------------------------------------------------------------
// C partials: ctx (64x2048) @ W4c (2048x1216). grid (19, 8), 256 thr.
// Output partC[ks][n][b].
// ---------------------------------------------------------------------------
__global__ __launch_bounds__(256) void k_gemm_C(const float* ctxT,
                                                const float* Wi, const float* Wf,
                                                const float* Wo, const float* Wg,
                                                float* partC)
{
    const int nt = blockIdx.x, ks = blockIdx.y, tid = threadIdx.x;
    const int n0 = nt*64, tx = tid & 15, ty = tid >> 4;
    __shared__ float As[16][64];
    __shared__ float Bs[16][64];
    float acc[4][4] = {};
    const int k0 = ks*256;
    for (int kb = 0; kb < 16; kb++) {
        const int kbase = k0 + kb*16;
#pragma unroll
        for (int i = 0; i < 4; i++) {
            int idx = tid + i*256;
            int kk = idx >> 6, bb = idx & 63;
            As[kk][bb] = ctxT[(kbase + kk)*64 + bb];
        }
#pragma unroll
        for (int i = 0; i < 4; i++) {
            int idx = tid + i*256;
            int kk = idx >> 6, nn = idx & 63;
            int n = n0 + nn, c = n >> 2, g = n & 3;
            const float* W = (g==0)?Wi:(g==1)?Wf:(g==2)?Wo:Wg;
            Bs[kk][nn] = (c < Hh) ? W[(2*Hh + kbase + kk)*Hh + c] : 0.0f;
        }
        __syncthreads();
#pragma unroll
        for (int kk = 0; kk < 16; kk++) {
            float4 av = *(const float4*)&As[kk][ty*4];
            float4 bv = *(const float4*)&Bs[kk][tx*4];
            fma16_(av, bv, acc);
        }
        __syncthreads();
    }
#pragma unroll
    for (int jn = 0; jn < 4; jn++) {
        float4 v = make_float4(acc[0][jn], acc[1][jn], acc[2][jn], acc[3][jn]);
        *(float4*)&partC[((ks*N4P) + n0 + tx*4 + jn)*64 + ty*4] = v;
    }
}

// ---------------------------------------------------------------------------
// gpre[t][n][b] = (E_t @ W4e)[n][b] + sum_ks partC[ks][n][b] + b4p[n].
// grid (19 nt, 31 t), 256 thr.  Layout [t][n][b]: recurrence reads coalesced
// over b (lane dim), 4 separate gate loads per thread.
// ---------------------------------------------------------------------------
__global__ __launch_bounds__(256) void k_gemm_gpre(const float* E,
                                                   const float* Wi, const float* Wf,
                                                   const float* Wo, const float* Wg,
                                                   const float* partC, const float* b4p,
                                                   float* gpre)
{
    const int nt = blockIdx.x, t = blockIdx.y, tid = threadIdx.x;
    const int n0 = nt*64, tx = tid & 15, ty = tid >> 4;
    __shared__ float As[16][64];
    __shared__ float Bs[16][64];
    float acc[4][4] = {};
    for (int kb = 0; kb < 19; kb++) {
        const int kbase = kb*16;
#pragma unroll
        for (int i = 0; i < 4; i++) {
            int idx = tid + i*256;
            int kk = idx >> 6, bb = idx & 63, j = kbase + kk;
            As[kk][bb] = (j < Hh) ? E[(t*Hh + j)*64 + bb] : 0.0f;
        }
#pragma unroll
        for (int i = 0; i < 4; i++) {
            int idx = tid + i*256;
            int kk = idx >> 6, nn = idx & 63, j = kbase + kk;
            int n = n0 + nn, c = n >> 2, g = n & 3;
            const float* W = (g==0)?Wi:(g==1)?Wf:(g==2)?Wo:Wg;
            Bs[kk][nn] = (j < Hh && c < Hh) ? W[j*Hh + c] : 0.0f;
        }
        __syncthreads();
#pragma unroll
        for (int kk = 0; kk < 16; kk++) {
            float4 av = *(const float4*)&As[kk][ty*4];
            float4 bv = *(const float4*)&Bs[kk][tx*4];
            fma16_(av, bv, acc);
        }
        __syncthreads();
    }
#pragma unroll
    for (int jn = 0; jn < 4; jn++) {
        const int n = n0 + tx*4 + jn;
        float4 ps = make_float4(0,0,0,0);
        for (int ks = 0; ks < 8; ks++) {
            const float4 v = *(const float4*)&partC[(ks*N4P + n)*64 + ty*4];
            ps.x += v.x; ps.y += v.y; ps.z += v.z; ps.w += v.w;
        }
        const float bv = b4p[n];
        float4 o;
        o.x = acc[0][jn] + ps.x + bv;
        o.y = acc[1][jn] + ps.y + bv;
        o.z = acc[2][jn] + ps.z + bv;
        o.w = acc[3][jn] + ps.w + bv;
        *(float4*)&gpre[((long)t*N4P + n)*64 + ty*4] = o;
    }
}

// ---------------------------------------------------------------------------
// pbias partials: ctx @ Wcp. grid (7, 8), 192 thr. Output ppb[ks][n][b].
// ---------------------------------------------------------------------------
__global__ __launch_bounds__(192) void k_gemm_pb(const float* ctxT, const float* Wcp,
                                                 float* ppb)
{
    const int nt = blockIdx.x, ks = blockIdx.y, tid = threadIdx.x;
    const int n0 = nt*48, tx = tid % 12, ty = tid / 12;
    __shared__ float As[16][64];
    __shared__ float Bs[16][48];
    float acc[4][4] = {};
    const int k0 = ks*256;
    for (int kb = 0; kb < 16; kb++) {
        const int kbase = k0 + kb*16;
        for (int idx = tid; idx < 1024; idx += 192) {
            int kk = idx >> 6, bb = idx & 63;
            As[kk][bb] = ctxT[(kbase + kk)*64 + bb];
        }
        for (int idx = tid; idx < 768; idx += 192) {
            int kk = idx / 48, nn = idx % 48, n = n0 + nn;
            Bs[kk][nn] = (n < Hh) ? Wcp[(kbase + kk)*Hh + n] : 0.0f;
        }
        __syncthreads();
#pragma unroll
        for (int kk = 0; kk < 16; kk++) {
            float4 av = *(const float4*)&As[kk][ty*4];
            float4 bv = *(const float4*)&Bs[kk][tx*4];
            fma16_(av, bv, acc);
        }
        __syncthreads();
    }
#pragma unroll
    for (int jn = 0; jn < 4; jn++) {
        float4 v = make_float4(acc[0][jn], acc[1][jn], acc[2][jn], acc[3][jn]);
        *(float4*)&ppb[((ks*NPP) + n0 + tx*4 + jn)*64 + ty*4] = v;
    }
}

// ---------------------------------------------------------------------------
// Recurrence with CUSTOM lightweight sync (no grid.sync, no L2 flush).
// 75 WGs x 512 thr, cooperative launch (co-residency guaranteed), WG s owns
// h-cols [4s,4s+4). Weight slice (16 gate cols x 300 k = 19.2 KB) in LDS,
// loaded once. Thread (kc,hl,b): k-half x col x batch.
// Per step: GEMV-half (150 coalesced cache-bypassing h loads + LDS-broadcast
// weights) -> LDS reduce -> gates -> h stored with relaxed AGENT atomics
// (write-through, visible at coherence point) -> per-WG epoch flag -> wave 0
// spins on 75 flags. Max skew between WGs is 1 step => race-free.
// ---------------------------------------------------------------------------
__global__ __launch_bounds__(512) void k_recs(const float* __restrict__ W4h_p,
                                              const float* __restrict__ gpre,
                                              const float* __restrict__ c0T,
                                              float* __restrict__ hT,
                                              int* __restrict__ flags)
{
    const int s = blockIdx.x, tid = threadIdx.x;
    const int b = tid & 63, w = tid >> 6, hl = w & 3, kc = w >> 2;
    __shared__ float wlds[300*16];        // [k][16 gate cols of this WG]
    __shared__ float psum[4*4*64];        // kc=1 partials: [hl][g][b]

    for (int i = tid; i < 300*16; i += 512)
        wlds[i] = W4h_p[(i >> 4)*N4P + 16*s + (i & 15)];

    float cst = 0.0f;
    if (w < 4) cst = c0T[(4*s + hl)*64 + b];
    __syncthreads();

    const int kbase = kc*150;
    const float* wl = wlds + kbase*16 + hl*4;

    for (int t = 1; t < Tt; t++) {
        // prefetch gate bias (this step, known address) early
        float gp0=0.f, gp1=0.f, gp2=0.f, gp3=0.f;
        if (w < 4) {
            const float* gp = gpre + ((long)(t-1)*N4P + 16*s + 4*hl)*64 + b;
            gp0 = gp[0]; gp1 = gp[64]; gp2 = gp[128]; gp3 = gp[192];
        }
        // GEMV half: h loads bypass caches (relaxed agent atomics) -> fresh
        const float* hsrc = hT + (t-1)*(Hh*64) + kbase*64 + b;
        float a0=0.f, a1=0.f, a2=0.f, a3=0.f;
#pragma unroll 10
        for (int k = 0; k < 150; k++) {
            const float hv = __hip_atomic_load(hsrc + k*64, __ATOMIC_RELAXED,
                                               __HIP_MEMORY_SCOPE_AGENT);
            const float4 wv = *(const float4*)(wl + k*16);
            a0 += hv*wv.x; a1 += hv*wv.y; a2 += hv*wv.z; a3 += hv*wv.w;
        }
        if (w >= 4) {
            psum[(hl*4+0)*64 + b] = a0;
            psum[(hl*4+1)*64 + b] = a1;
            psum[(hl*4+2)*64 + b] = a2;
            psum[(hl*4+3)*64 + b] = a3;
        }
        __syncthreads();
        if (w < 4) {
            a0 += psum[(hl*4+0)*64 + b] + gp0;
            a1 += psum[(hl*4+1)*64 + b] + gp1;
            a2 += psum[(hl*4+2)*64 + b] + gp2;
            a3 += psum[(hl*4+3)*64 + b] + gp3;
            const float ig = sigmf_(a0), fg = sigmf_(a1), og = sigmf_(a2);
            const float gg = tanhf(a3);
            cst = fg*cst + ig*gg;
            const float h = og*tanhf(cst);
            __hip_atomic_store(&hT[t*(Hh*64) + (4*s + hl)*64 + b], h,
                               __ATOMIC_RELAXED, __HIP_MEMORY_SCOPE_AGENT);
        }
        __syncthreads();   // (A) h stores drained (vmcnt 0), psum reusable
        if (t < Tt - 1) {
            if (tid == 0)
                __hip_atomic_store(&flags[s], t, __ATOMIC_RELAXED,
                                   __HIP_MEMORY_SCOPE_AGENT);
            if (tid < 64) {
                for (;;) {
                    const int v0 = __hip_atomic_load(&flags[tid], __ATOMIC_RELAXED,
                                                     __HIP_MEMORY_SCOPE_AGENT);
                    const int v1 = __hip_atomic_load(&flags[tid+64], __ATOMIC_RELAXED,
                                                     __HIP_MEMORY_SCOPE_AGENT);
                    if (__all(v0 >= t && v1 >= t)) break;
                    __builtin_amdgcn_s_sleep(2);
                }
            }
            __syncthreads();  // (B) release all waves into step t+1
        }
    }
}

// ---------------------------------------------------------------------------
// tmp[t][j][b] = E[t][j][b] + (h_{t+1} @ Whp)[j][b] + pbias[j][b].
// grid (7 nt, 31 t), 192 thr.
// ---------------------------------------------------------------------------
__global__ __launch_bounds__(192) void k_gemm_tmp(const float* hT, const float* Whp,
                                                  const float* E, const float* ppb,
                                                  const float* pb_b, float* tmpT)
{
    const int nt = blockIdx.x, ti = blockIdx.y, tid = threadIdx.x;
    const int n0 = nt*48, tx = tid % 12, ty = tid / 12;
    __shared__ float As[16][64];
    __shared__ float Bs[16][48];
    float acc[4][4] = {};
    for (int kb = 0; kb < 19; kb++) {
        const int kbase = kb*16;
        for (int idx = tid; idx < 1024; idx += 192) {
            int kk = idx >> 6, bb = idx & 63, j = kbase + kk;
            As[kk][bb] = (j < Hh) ? hT[((ti+1)*Hh + j)*64 + bb] : 0.0f;
        }
        for (int idx = tid; idx < 768; idx += 192) {
            int kk = idx / 48, nn = idx % 48, j = kbase + kk, n = n0 + nn;
            Bs[kk][nn] = (j < Hh && n < Hh) ? Whp[j*Hh + n] : 0.0f;
        }
        __syncthreads();
#pragma unroll
        for (int kk = 0; kk < 16; kk++) {
            float4 av = *(const float4*)&As[kk][ty*4];
            float4 bv = *(const float4*)&Bs[kk][tx*4];
            fma16_(av, bv, acc);
        }
        __syncthreads();
    }
#pragma unroll
    for (int i = 0; i < 4; i++) {
        const int bb = ty*4 + i;
#pragma unroll
        for (int j = 0; j < 4; j++) {
            const int n = n0 + tx*4 + j;
            if (n < KOP) {
                float v = acc[i][j];
                if (n < Hh) {
                    float pb = pb_b[n];
                    for (int ks = 0; ks < 8; ks++) pb += ppb[(ks*NPP + n)*64 + bb];
                    v += E[(ti*Hh + n)*64 + bb] + pb;
                }
                tmpT[(ti*KOP + n)*64 + bb] = v;
            }
        }
    }
}

// Stage B: out[:, t+1, :] = tmp @ Wop + bop. grid (7, 31).
__global__ __launch_bounds__(192) void k_predb(const float* tmpT, const float* Wop,
                                               const float* bop, float* out)
{
    const int nt = blockIdx.x, ti = blockIdx.y, tid = threadIdx.x;
    const int n0 = nt*48, tx = tid % 12, ty = tid / 12;
    __shared__ float As[16][64];
    __shared__ float Bs[16][48];
    float acc[4][4] = {};
    const float* Asrc = tmpT + ti*KOP*64;

    for (int kb = 0; kb < 19; kb++) {
        const int kbase = kb*16;
        for (int idx = tid; idx < 1024; idx += 192) {
            int kk = idx >> 6, bb = idx & 63;
            As[kk][bb] = Asrc[(kbase + kk)*64 + bb];
        }
        for (int idx = tid; idx < 768; idx += 192) {
            int kk = idx / 48, nn = idx % 48, j = kbase + kk, n = n0 + nn;
            Bs[kk][nn] = (j < Hh && n < Hh) ? Wop[j*Hh + n] : 0.0f;
        }
        __syncthreads();
#pragma unroll
        for (int kk = 0; kk < 16; kk++) {
            float4 av = *(const float4*)&As[kk][ty*4];
            float4 bv = *(const float4*)&Bs[kk][tx*4];
            fma16_(av, bv, acc);
        }
        __syncthreads();
    }
#pragma unroll
    for (int i = 0; i < 4; i++) {
        const int bb = ty*4 + i;
#pragma unroll
        for (int j = 0; j < 4; j++) {
            const int n = n0 + tx*4 + j;
            if (n < Hh)
                out[(bb*Tt + (ti+1))*Hh + n] = acc[i][j] + bop[n];
        }
    }
}

// ---------------------------------------------------------------------------
extern "C" void kernel_launch(void* const* d_in, const int* in_sizes, int n_in,
                              void* d_out, int out_size, void* d_ws, size_t ws_size,
                              hipStream_t stream)
{
    const float* enc    = (const float*)d_in[0];
    const int*   caps   = (const int*)  d_in[1];
    const float* emb    = (const float*)d_in[2];
    const float* Wh0    = (const float*)d_in[3];
    const float* bh0    = (const float*)d_in[4];
    const float* Wc0    = (const float*)d_in[5];
    const float* bc0    = (const float*)d_in[6];
    const float* We_enc = (const float*)d_in[7];
    const float* We_hid = (const float*)d_in[8];
    const float* be     = (const float*)d_in[9];
    const float* Wi     = (const float*)d_in[10];
    const float* bi     = (const float*)d_in[11];
    const float* Wf     = (const float*)d_in[12];
    const float* bf     = (const float*)d_in[13];
    const float* Wo     = (const float*)d_in[14];
    const float* bo     = (const float*)d_in[15];
    const float* Wg     = (const float*)d_in[16];
    const float* bg     = (const float*)d_in[17];
    const float* Wcp    = (const float*)d_in[18];
    const float* bcp    = (const float*)d_in[19];
    const float* Whp    = (const float*)d_in[20];
    const float* bhp    = (const float*)d_in[21];
    const float* Wop    = (const float*)d_in[22];
    const float* bop    = (const float*)d_in[23];
    float* out = (float*)d_out;
    (void)We_hid; (void)be;   // softmax is invariant to the h-term: unused.

    // Workspace carve-up (floats).
    float* w = (float*)d_ws;
    float* W4h_p = w; w += KH*N4P;       //   369,664
    float* b4p   = w; w += N4P;
    float* pb_b  = w; w += NPP;
    float* bhc   = w; w += NH;
    float* e_enc = w; w += Bb*Cc;
    float* ctxT  = w; w += Ff*64;        //   131,072
    float* hT    = w; w += Tt*Hh*64;     //   614,400  h_t, t=0..31, [t][col][b]
    float* E     = w; w += 31*Hh*64;     //   595,200  emb_prev, [t][j][b]
    float* c0T   = w; w += KH*64;        //    19,456  [col][b]
    float* gpre  = w; w += 31*N4P*64;    // 2,412,544  [t][n][b]
    float* partC = w; w += 8*N4P*64;     //   622,592  [ks][n][b]
    float* ppb   = w; w += 8*NPP*64;     //   172,032  [ks][n][b]
    float* tmpT  = w; w += 31*KOP*64;    //   603,136  [t][j][b]
    int*   flags = (int*)w; w += 128;    //   epoch flags (reset by k_pack)
    // init-phase aliases (dead before tmpT is written by k_gemm_tmp)
    float* meanT = tmpT;                 // 131,072
    float* parth = tmpT + 131072;        // 319,488 (fits 603,136)
    (void)ws_size; (void)in_sizes; (void)n_in; (void)out_size;

    k_pack<<<512, 256, 0, stream>>>(Wi, Wf, Wo, Wg, bi, bf, bo, bg,
                                    bcp, bhp, bh0, bc0,
                                    W4h_p, b4p, pb_b, bhc, flags);
    k_meanT<<<dim3(8, 64), 256, 0, stream>>>(enc, meanT);
    k_eenc <<<dim3(25, 64), 256, 0, stream>>>(enc, We_enc, e_enc);
    k_embed<<<2325, 256, 0, stream>>>(caps, emb, E);
    k_bos  <<<75, 256, 0, stream>>>(emb, out);
    k_ctx  <<<dim3(8, 64), 256, 0, stream>>>(enc, e_enc, ctxT);
    k_gemm_h0<<<dim3(13, 8), 192, 0, stream>>>(meanT, Wh0, Wc0, parth);
    k_h0fin2<<<64, 256, 0, stream>>>(parth, bhc, hT, c0T);
    k_gemm_C<<<dim3(19, 8), 256, 0, stream>>>(ctxT, Wi, Wf, Wo, Wg, partC);
    k_gemm_gpre<<<dim3(19, 31), 256, 0, stream>>>(E, Wi, Wf, Wo, Wg, partC, b4p, gpre);
    k_gemm_pb<<<dim3(7, 8), 192, 0, stream>>>(ctxT, Wcp, ppb);

    // Recurrence: cooperative launch for co-residency; custom flag sync inside.
    {
        void* rargs[] = { (void*)&W4h_p, (void*)&gpre, (void*)&c0T,
                          (void*)&hT, (void*)&flags };
        hipLaunchCooperativeKernel((const void*)k_recs, dim3(NWG), dim3(512),
                                   rargs, 0, stream);
    }

    k_gemm_tmp<<<dim3(7, 31), 192, 0, stream>>>(hT, Whp, E, ppb, pb_b, tmpT);
    k_predb<<<dim3(7, 31), 192, 0, stream>>>(tmpT, Wop, bop, out);
}